// Round 10
// baseline (480.371 us; speedup 1.0000x reference)
//
#include <hip/hip_runtime.h>
#include <hip/hip_bf16.h>
#include <cstdint>
#include <cstddef>

typedef __hip_bfloat16 bf16;
typedef __attribute__((ext_vector_type(8))) short bf16x8;
typedef __attribute__((ext_vector_type(4))) float f32x4;

#define NN 50000
#define NE 400000

__device__ __forceinline__ float bf2f(unsigned short u) {
    return __uint_as_float(((unsigned)u) << 16);
}
__device__ __forceinline__ unsigned short f2bf(float f) {
    __hip_bfloat16 h = __float2bfloat16(f);
    return *reinterpret_cast<unsigned short*>(&h);
}
__device__ __forceinline__ float fin(float v) {
    return (v == v && v > -1e30f && v < 1e30f) ? v : 0.0f;
}
__device__ __forceinline__ float rd(const void* p, int i, int f) {
    return f ? ((const float*)p)[i] : bf2f(((const unsigned short*)p)[i]);
}

// async global -> LDS, 16B per lane, dest = wave-uniform base + lane*16
__device__ __forceinline__ void gl16(const void* g, void* l) {
    __builtin_amdgcn_global_load_lds(
        (const __attribute__((address_space(1))) unsigned int*)g,
        (__attribute__((address_space(3))) unsigned int*)l, 16, 0, 0);
}

// ---- inline dtype probe: 1 fp32 / 0 bf16. wave 0 computes, LDS-broadcast. ----
__device__ __forceinline__ int probe_flag(const unsigned* __restrict__ p, int words,
                                          int* sflag) {
    if (threadIdx.x < 64) {
        int lane = threadIdx.x;
        int zc = 0, bc = 0;
        #pragma unroll
        for (int c = 0; c < 4; ++c) {
            int idx = c * 64 + lane;
            int act = idx < words;
            unsigned w = act ? p[idx] : 0u;
            int isz = act && (w == 0u);
            int e = (w >> 7) & 0xFF;
            int isb = act && !isz && (e >= 100 && e <= 140);
            zc += __popcll(__ballot(isz));
            bc += __popcll(__ballot(isb));
        }
        int nz = words - zc;
        if (lane == 0) *sflag = (nz == 0 || 2 * bc >= nz) ? 0 : 1;
    }
    __syncthreads();
    return *sflag;
}

// ---- mega-prep: [wsplit segs 0..7 | bias 8 blocks | xin 3125 blocks] ----
struct Prep {
    const void* wsrc[8];
    unsigned short* pwh[8];
    unsigned short* pwl[8];
    int K[8], M[8], Kp[8];
    int b0[8];
    int biasStart, xinStart;
    const void* bsrc[8];
    int bM[8], bmp[8], bmo[8];
    float* ball;
    const void* x;
    const float* dinv;
    unsigned short* xs;
};

__global__ void k_prep(Prep P) {
    __shared__ int sflag;
    const int bid = blockIdx.x;

    if (bid >= P.xinStart) {
        // ---- xin: xs = bf16(x * dinv), stride 128 ----
        int f = probe_flag((const unsigned*)P.x, 256, &sflag);
        int t = (bid - P.xinStart) * 256 + threadIdx.x;
        if (t >= NN * 16) return;
        int i = t >> 4, c = (t & 15) * 8;
        float d = P.dinv[i];
        const float* xf = (const float*)P.x + (size_t)i * 128 + c;
        const unsigned short* xb = (const unsigned short*)P.x + (size_t)i * 128 + c;
        unsigned short o[8];
        #pragma unroll
        for (int j = 0; j < 8; ++j)
            o[j] = f2bf(fin(f ? xf[j] : bf2f(xb[j])) * d);
        *(uint4*)(P.xs + (size_t)i * 128 + c) = *(uint4*)o;
        return;
    }
    if (bid >= P.biasStart) {
        // ---- bias: zero-padded to bmp[l] ----
        int l = bid - P.biasStart;
        int words = P.bM[l] >> 1; if (words > 256) words = 256;
        int f = probe_flag((const unsigned*)P.bsrc[l], words, &sflag);
        int i = threadIdx.x;
        if (i < P.bmp[l])
            P.ball[P.bmo[l] + i] = (i < P.bM[l]) ? fin(rd(P.bsrc[l], i, f)) : 0.0f;
        return;
    }
    // ---- weight split: transposed bf16 hi/lo, [rows][Kp], zero-padded ----
    int seg = 0;
    #pragma unroll
    for (int t = 1; t < 8; ++t) if (bid >= P.b0[t]) seg = t;
    int words = (P.K[seg] * P.M[seg]) >> 1; if (words > 256) words = 256;
    int f = probe_flag((const unsigned*)P.wsrc[seg], words, &sflag);
    int n = bid - P.b0[seg];
    int k = threadIdx.x;
    int Kp = P.Kp[seg];
    if (k >= Kp) return;
    float v = 0.0f;
    if (k < P.K[seg] && n < P.M[seg])
        v = fin(rd(P.wsrc[seg], k * P.M[seg] + n, f));
    unsigned short hi = f2bf(v);
    unsigned short lo = f2bf(v - bf2f(hi));
    P.pwh[seg][(size_t)n * Kp + k] = hi;
    P.pwl[seg][(size_t)n * Kp + k] = lo;
}

// ---- repack edge list + degree count; ei int32/int64 flag computed inline ----
__global__ void k_repack(const int* __restrict__ ei,
                         int* __restrict__ src, int* __restrict__ dst,
                         int* __restrict__ deg) {
    __shared__ int sAny;
    if (threadIdx.x < 64) {
        int lane = threadIdx.x;
        int any = 0;
        #pragma unroll
        for (int c = 0; c < 32; ++c) {
            int idx = c * 64 + lane;
            int v = ei[2 * idx + 1];
            any |= (__ballot(v != 0) != 0ull) ? 1 : 0;
        }
        if (lane == 0) sAny = any;
    }
    __syncthreads();
    int f = sAny;
    int e = blockIdx.x * blockDim.x + threadIdx.x;
    if (e >= NE) return;
    int s, d;
    if (f) { s = ei[e]; d = ei[NE + e]; }
    else   { s = ei[2 * e]; d = ei[2 * (NE + e)]; }
    s = min(max(s, 0), NN - 1);
    d = min(max(d, 0), NN - 1);
    src[e] = s;
    dst[e] = d;
    atomicAdd(&deg[d], 1);
}

__global__ void k_scan1(const int* __restrict__ deg, int* __restrict__ rowp,
                        int* __restrict__ part) {
    __shared__ int s[512];
    int tid = threadIdx.x, i = blockIdx.x * 512 + tid;
    int v = (i < NN) ? deg[i] : 0;
    s[tid] = v;
    __syncthreads();
    for (int off = 1; off < 512; off <<= 1) {
        int t = (tid >= off) ? s[tid - off] : 0;
        __syncthreads();
        s[tid] += t;
        __syncthreads();
    }
    if (i < NN) rowp[i] = s[tid] - v;
    if (tid == 511) part[blockIdx.x] = s[511];
}

// ---- scan finalize: per-block partial reduce, dinv, cursor=0 ----
__global__ void k_scan3b(int* __restrict__ rowp, const int* __restrict__ part,
                         const int* __restrict__ deg, float* __restrict__ dinv,
                         int* __restrict__ cursor) {
    __shared__ int sS;
    const int b = blockIdx.x;
    const int g = b >> 1;
    if (threadIdx.x < 64) {
        int lane = threadIdx.x;
        int v = 0;
        if (lane < g) v += part[lane];
        if (64 + lane < g) v += part[64 + lane];
        #pragma unroll
        for (int o = 1; o < 64; o <<= 1) v += __shfl_xor(v, o);
        if (lane == 0) sS = v;
    }
    __syncthreads();
    int S = sS;
    int i = b * 256 + threadIdx.x;
    if (i < NN) {
        rowp[i] += S;
        dinv[i] = rsqrtf((float)deg[i] + 1.0f);
        cursor[i] = 0;
    }
    if (i == 0) rowp[NN] = NE;
}

__global__ void k_fill(const int* __restrict__ src, const int* __restrict__ dst,
                       const int* __restrict__ rowp, int* __restrict__ cursor,
                       int* __restrict__ colv) {
    int e = blockIdx.x * blockDim.x + threadIdx.x;
    if (e >= NE) return;
    int d = dst[e];
    int p = atomicAdd(&cursor[d], 1);
    colv[rowp[d] + p] = src[e];
}

// ---- CSR gather: out[i]=dinv[i]*(in[i]+sum in[colv[j]]) ----
__launch_bounds__(256)
__global__ void k_gather(const unsigned short* __restrict__ in, int istride,
                         unsigned short* __restrict__ out, int ostride, int lanes,
                         const int* __restrict__ rowp, const int* __restrict__ colv,
                         const float* __restrict__ dinv) {
    const int node = blockIdx.x * 4 + (threadIdx.x >> 6);
    if (node >= NN) return;
    const int lane = threadIdx.x & 63;
    const int beg = rowp[node], end = rowp[node + 1];
    float a[8] = {0.f, 0.f, 0.f, 0.f, 0.f, 0.f, 0.f, 0.f};
    auto accq = [&](uint4 q) {
        unsigned v[4] = {q.x, q.y, q.z, q.w};
        #pragma unroll
        for (int t = 0; t < 4; ++t) {
            a[2 * t] += bf2f(v[t] & 0xFFFF); a[2 * t + 1] += bf2f(v[t] >> 16);
        }
    };
    if (lanes <= 16) {
        const int slot = lane >> 4;
        const int l8 = lane & 15;
        const bool on = l8 < lanes;
        const size_t off = (size_t)l8 * 8;
        if (slot == 0 && on)
            accq(*(const uint4*)(in + (size_t)node * istride + off));
        for (int j = beg + slot; j < end; j += 4) {
            const int s = colv[j];
            if (on) accq(*(const uint4*)(in + (size_t)s * istride + off));
        }
        #pragma unroll
        for (int t = 0; t < 8; ++t) {
            a[t] += __shfl_xor(a[t], 16);
            a[t] += __shfl_xor(a[t], 32);
        }
        if (lane < lanes) {
            float d = dinv[node];
            unsigned short o[8];
            #pragma unroll
            for (int t = 0; t < 8; ++t) o[t] = f2bf(a[t] * d);
            *(uint4*)(out + (size_t)node * ostride + (size_t)lane * 8) = *(uint4*)o;
        }
    } else {
        const bool on = lane < lanes;
        const size_t off = (size_t)lane * 8;
        if (on) accq(*(const uint4*)(in + (size_t)node * istride + off));
        int j = beg;
        for (; j + 1 < end; j += 2) {
            int s0 = colv[j], s1 = colv[j + 1];
            if (on) {
                uint4 q0 = *(const uint4*)(in + (size_t)s0 * istride + off);
                uint4 q1 = *(const uint4*)(in + (size_t)s1 * istride + off);
                accq(q0); accq(q1);
            }
        }
        if (j < end) {
            int s0 = colv[j];
            if (on) accq(*(const uint4*)(in + (size_t)s0 * istride + off));
        }
        if (on) {
            float d = dinv[node];
            unsigned short o[8];
            #pragma unroll
            for (int t = 0; t < 8; ++t) o[t] = f2bf(a[t] * d);
            *(uint4*)(out + (size_t)node * ostride + off) = *(uint4*)o;
        }
    }
}

// ---- merged GEMM side params ----
struct GSide {
    const unsigned short* A;
    const unsigned short* Wh;
    const unsigned short* Wl;
    const float* bias;
    void* out;
    int Kp, ostride, M, OutW, act;
};

// ---- MFMA GEMM: 256x64 tile (wave = 64 rows x 64 cols -> 32 MFMA per K-step,
//      2x work per barrier vs r9), 48KB LDS -> 3 blocks/CU. r5-proven pipeline:
//      gl16 staging (6 ops/wave, steady vmcnt(6)), XOR-swizzled LDS, 2-ahead
//      counted-vmcnt (never drain in-loop), XCD group swizzle, LDS epilogue. ----
__launch_bounds__(256, 3)
__global__ void k_mgemm(GSide s0, GSide s1, int ySplit, int NY, int NB, int astride,
                        const float* __restrict__ dinv) {
    __shared__ __align__(16) unsigned char ldsraw[49152];
    auto sA  = reinterpret_cast<unsigned short (*)[256][32]>(ldsraw);          // 2x16K
    auto sBh = reinterpret_cast<unsigned short (*)[64][32]>(ldsraw + 32768);   // 2x4K
    auto sBl = reinterpret_cast<unsigned short (*)[64][32]>(ldsraw + 40960);   // 2x4K

    const int tid = threadIdx.x;
    const int wave = tid >> 6, lane = tid & 63;
    const int quad = lane >> 4, m16 = lane & 15;

    // XCD grouping: the NY col-blocks of one x-tile land on the same XCD
    const int NBa = NB & ~7;
    const int swcut = NBa * NY;
    int b = blockIdx.x, x, yv;
    if (b < swcut) {
        x = (b / (8 * NY)) * 8 + (b & 7);
        yv = (b >> 3) % NY;
    } else {
        int r = b - swcut, rem = NB - NBa;
        x = rem ? (NBa + r % rem) : 0;
        yv = rem ? (r / rem) : 0;
    }

    GSide S; int ycol;
    if (yv < ySplit) { S = s0; ycol = yv; }
    else             { S = s1; ycol = yv - ySplit; }
    const int row0 = x * 256, col0 = ycol * 64;
    const int Kp = S.Kp;

    // staging: lane -> (row, 16B unit); A: wave stages rows [wave*64, +64)
    //          B: wave stages rows [wave*16, +16) of the 64-row col panel
    const int lr = lane >> 2;
    const int swz = ((lane >> 2) ^ (lane >> 4)) & 3;
    const int su = ((lane & 3) ^ swz) * 8;

    const unsigned short* gA[4];
    #pragma unroll
    for (int c = 0; c < 4; ++c) {
        int ar = row0 + wave * 64 + c * 16 + lr;
        if (ar >= NN) ar = NN - 1;
        gA[c] = S.A + (size_t)ar * astride + su;
    }
    const int br = col0 + wave * 16 + lr;
    const unsigned short* gBh1 = S.Wh + (size_t)br * Kp + su;
    const unsigned short* gBl1 = S.Wl + (size_t)br * Kp + su;

    f32x4 zz = {0.f, 0.f, 0.f, 0.f};
    f32x4 acc[4][4];
    #pragma unroll
    for (int i = 0; i < 4; ++i)
        #pragma unroll
        for (int j = 0; j < 4; ++j) acc[i][j] = zz;

    const int rs = (quad ^ ((m16 & 3) ^ ((m16 >> 2) & 3))) * 8;
    const int nk = Kp >> 5;

    auto stage = [&](int bb, int k0) {           // 6 vmem ops per wave
        gl16(gA[0] + k0, &sA[bb][wave * 64][0]);
        gl16(gA[1] + k0, &sA[bb][wave * 64 + 16][0]);
        gl16(gA[2] + k0, &sA[bb][wave * 64 + 32][0]);
        gl16(gA[3] + k0, &sA[bb][wave * 64 + 48][0]);
        gl16(gBh1 + k0,  &sBh[bb][wave * 16][0]);
        gl16(gBl1 + k0,  &sBl[bb][wave * 16][0]);
    };

    // 2-ahead prologue: stages 0 and 1 in flight (6 vmem ops each)
    stage(0, 0);
    if (nk > 1) stage(1, 32);

    for (int ks = 0; ks < nk; ++ks) {
        const int cur = ks & 1;
        // wait only MY stage-ks loads (6 newer from stage ks+1 stay in flight)
        if (ks + 1 < nk) asm volatile("s_waitcnt vmcnt(6)" ::: "memory");
        else             asm volatile("s_waitcnt vmcnt(0)" ::: "memory");
        __builtin_amdgcn_s_barrier();        // all waves' stage-ks landed
        bf16x8 fa[4], fh[4], fl[4];
        #pragma unroll
        for (int i = 0; i < 4; ++i)
            fa[i] = *(const bf16x8*)&sA[cur][wave * 64 + i * 16 + m16][rs];
        #pragma unroll
        for (int j = 0; j < 4; ++j) {
            fh[j] = *(const bf16x8*)&sBh[cur][j * 16 + m16][rs];
            fl[j] = *(const bf16x8*)&sBl[cur][j * 16 + m16][rs];
        }
        asm volatile("s_waitcnt lgkmcnt(0)" ::: "memory");
        __builtin_amdgcn_sched_barrier(0);
        __builtin_amdgcn_s_barrier();        // buf cur consumed -> free to overwrite
        if (ks + 2 < nk) stage(cur, (ks + 2) * 32);   // refill freed buffer
        #pragma unroll
        for (int i = 0; i < 4; ++i)
            #pragma unroll
            for (int j = 0; j < 4; ++j) {
                acc[i][j] = __builtin_amdgcn_mfma_f32_16x16x32_bf16(fa[i], fh[j], acc[i][j], 0, 0, 0);
                acc[i][j] = __builtin_amdgcn_mfma_f32_16x16x32_bf16(fa[i], fl[j], acc[i][j], 0, 0, 0);
            }
    }

    // ---- epilogue: stage per-wave 16x64 f32 tile in LDS, store coalesced ----
    float* eps = (float*)(ldsraw + (size_t)wave * 4352);
    #pragma unroll
    for (int i = 0; i < 4; ++i) {
        #pragma unroll
        for (int j = 0; j < 4; ++j) {
            int col = col0 + j * 16 + m16;
            float bcol = (col < S.M) ? S.bias[col] : 0.0f;
            #pragma unroll
            for (int r = 0; r < 4; ++r) {
                float v = acc[i][j][r] + bcol;
                if (S.act) v = (col < S.M) ? 1.0f / (1.0f + __expf(-v)) : 0.0f;
                else       v = (col < S.M) ? fmaxf(v, 0.0f) : 0.0f;
                eps[(quad * 4 + r) * 68 + j * 16 + m16] = v;
            }
        }
        asm volatile("s_waitcnt lgkmcnt(0)" ::: "memory");
        __builtin_amdgcn_sched_barrier(0);
        #pragma unroll
        for (int it = 0; it < 4; ++it) {
            int lr2 = it * 4 + (lane >> 4);
            int c4 = (lane & 15) * 4;
            float4 w = *(float4*)&eps[lr2 * 68 + c4];
            int grow = row0 + wave * 64 + i * 16 + lr2;
            int gcol = col0 + c4;
            if (grow < NN && gcol < S.OutW) {
                if (S.act) {
                    // final outputs: never re-read -> nontemporal, keep L2 for A
                    float* dp = (float*)S.out + (size_t)grow * S.ostride + gcol;
                    __builtin_nontemporal_store(w.x, dp);
                    __builtin_nontemporal_store(w.y, dp + 1);
                    __builtin_nontemporal_store(w.z, dp + 2);
                    __builtin_nontemporal_store(w.w, dp + 3);
                } else {
                    float d = dinv[grow];
                    unsigned o0 = f2bf(w.x * d) | ((unsigned)f2bf(w.y * d) << 16);
                    unsigned o1 = f2bf(w.z * d) | ((unsigned)f2bf(w.w * d) << 16);
                    uint2 u; u.x = o0; u.y = o1;
                    *(uint2*)((unsigned short*)S.out + (size_t)grow * S.ostride + gcol) = u;
                }
            }
        }
        asm volatile("s_waitcnt lgkmcnt(0)" ::: "memory");
        __builtin_amdgcn_sched_barrier(0);
    }
}

__global__ void k_sentinel(float* __restrict__ out, int n) {
    int i = blockIdx.x * blockDim.x + threadIdx.x;
    if (i < n) out[i] = 4.0f;
}

extern "C" void kernel_launch(void* const* d_in, const int* in_sizes, int n_in,
                              void* d_out, int out_size, void* d_ws, size_t ws_size,
                              hipStream_t stream) {
    const int* ei = (const int*)d_in[1];
    float* out_e = (float*)d_out;
    float* out_v = out_e + (size_t)NN * 256;

    // weight storage: l=0 merged [W1e pad168 | W1n pad->384] x128; l=4 unused
    const int KpW[8] = {128, 192, 192, 224, 0, 128, 128, 128};
    const int MpW[8] = {384, 256, 256, 256, 0, 128, 128, 128};

    char* wsb = (char*)d_ws;
    size_t o = 0;
    auto align = [](size_t v) { return (v + 255) & ~(size_t)255; };
    int*   colv   = (int*)(wsb + o);  o = align(o + (size_t)NE * 4);
    int*   deg    = (int*)(wsb + o);  o = align(o + (size_t)NN * 4);
    int*   cursor = (int*)(wsb + o);  o = align(o + (size_t)NN * 4);
    int*   rowp   = (int*)(wsb + o);  o = align(o + (size_t)(NN + 1) * 4);
    int*   part   = (int*)(wsb + o);  o = align(o + 512);
    float* dinv   = (float*)(wsb + o); o = align(o + (size_t)NN * 4);
    unsigned short* wh[8]; unsigned short* wl[8];
    for (int l = 0; l < 8; ++l) {
        size_t wel = (size_t)MpW[l] * KpW[l];
        wh[l] = (unsigned short*)(wsb + o); o = align(o + wel * 2);
        wl[l] = (unsigned short*)(wsb + o); o = align(o + wel * 2);
    }
    float* ball = (float*)(wsb + o); o = align(o + 1376 * 4);
    unsigned short* bufA = (unsigned short*)(wsb + o); o = align(o + (size_t)NN * 352 * 2);
    unsigned short* bufB = (unsigned short*)(wsb + o); o = align(o + (size_t)NN * 352 * 2);
    int* src32 = (int*)bufB;
    int* dst32 = src32 + NE;
    if (o > ws_size) {
        k_sentinel<<<(out_size + 255) / 256, 256, 0, stream>>>(out_e, out_size);
        return;
    }

    // bias layout: [b1e 168 | b1n 128 | b2e 192 | b2n 128 | b3e 224 | b3n 128 | b4e 256 | b4n 128]
    const int moff[8] = {0, 296, 616, 968, 168, 488, 840, 1224};
    const int mpad[8] = {168, 192, 224, 256, 128, 128, 128, 128};

    const int EB = (NE + 255) / 256;
    const int NB512 = (NN + 511) / 512;
    const int GXM = (NN + 255) / 256;         // 196 row-tiles (256 rows each)
    const int GN = (NN + 3) / 4;

    // ---- CSR build ----
    hipMemsetAsync(deg, 0, (size_t)NN * 4, stream);
    k_repack<<<EB, 256, 0, stream>>>(ei, src32, dst32, deg);
    k_scan1<<<NB512, 512, 0, stream>>>(deg, rowp, part);
    k_scan3b<<<(NN + 255) / 256, 256, 0, stream>>>(rowp, part, deg, dinv, cursor);
    k_fill<<<EB, 256, 0, stream>>>(src32, dst32, rowp, cursor, colv);

    // ---- mega-prep: weight split (hi/lo) + biases + xin, one launch ----
    {
        Prep P;
        const void* srcs[8] = {d_in[2], d_in[10], d_in[4], d_in[12],
                               d_in[6], d_in[14], d_in[8], d_in[16]};
        unsigned short* whp[8] = {wh[0], wh[0] + 168 * 128, wh[1], wh[5],
                                  wh[2], wh[6], wh[3], wh[7]};
        unsigned short* wlp[8] = {wl[0], wl[0] + 168 * 128, wl[1], wl[5],
                                  wl[2], wl[6], wl[3], wl[7]};
        const int Ks[8]   = {128, 128, 166, 128, 192, 128, 218, 128};
        const int Ms[8]   = {166, 128, 192, 128, 218, 128, 256, 128};
        const int Kps[8]  = {128, 128, 192, 128, 192, 128, 224, 128};
        const int rows[8] = {168, 216, 256, 128, 256, 128, 256, 128};
        int acc = 0;
        for (int s = 0; s < 8; ++s) {
            P.wsrc[s] = srcs[s]; P.pwh[s] = whp[s]; P.pwl[s] = wlp[s];
            P.K[s] = Ks[s]; P.M[s] = Ms[s]; P.Kp[s] = Kps[s];
            P.b0[s] = acc; acc += rows[s];
        }
        P.biasStart = acc;            // 1536
        P.xinStart = acc + 8;         // 1544
        const int bMv[8] = {166, 192, 218, 256, 128, 128, 128, 128};
        for (int l = 0; l < 8; ++l) {
            P.bsrc[l] = d_in[3 + 2 * l];
            P.bM[l] = bMv[l]; P.bmp[l] = mpad[l]; P.bmo[l] = moff[l];
        }
        P.ball = ball;
        P.x = d_in[0];
        P.dinv = dinv;
        P.xs = bufA;
        const int xinBlocks = (NN * 16 + 255) / 256;   // 3125
        k_prep<<<P.xinStart + xinBlocks, 256, 0, stream>>>(P);
    }

    // gather0: bufA(128) -> bufB (stride 128)
    k_gather<<<GN, 256, 0, stream>>>(bufA, 128, bufB, 128, 16, rowp, colv, dinv);

    // L1 merged (e+n): bufB(128) -> bufA (stride 296 = [e168 | n128]), 5 col-blocks
    {
        GSide s0 = {bufB, wh[0], wl[0], ball, bufA, 128, 296, 296, 296, 0};
        k_mgemm<<<GXM * 5, 256, 0, stream>>>(s0, s0, 5, 5, GXM, 128, dinv);
    }
    k_gather<<<GN, 256, 0, stream>>>(bufA, 296, bufB, 296, 37, rowp, colv, dinv);

    // L2: e (K=192, 3 col-blocks) + n (K=128, 2 col-blocks), out stride 320
    {
        GSide s0 = {bufB, wh[1], wl[1], ball + 296, bufA, 192, 320, 192, 192, 0};
        GSide s1 = {bufB + 168, wh[5], wl[5], ball + 488, bufA + 192, 128, 320, 128, 128, 0};
        k_mgemm<<<GXM * 5, 256, 0, stream>>>(s0, s1, 3, 5, GXM, 296, dinv);
    }
    k_gather<<<GN, 256, 0, stream>>>(bufA, 320, bufB, 320, 40, rowp, colv, dinv);

    // L3: e (K=192, 4 col-blocks -> 224 wide) + n (2), out stride 352
    {
        GSide s0 = {bufB, wh[2], wl[2], ball + 616, bufA, 192, 352, 218, 224, 0};
        GSide s1 = {bufB + 192, wh[6], wl[6], ball + 840, bufA + 224, 128, 352, 128, 128, 0};
        k_mgemm<<<GXM * 6, 256, 0, stream>>>(s0, s1, 4, 6, GXM, 320, dinv);
    }
    k_gather<<<GN, 256, 0, stream>>>(bufA, 352, bufB, 352, 44, rowp, colv, dinv);

    // L4: sigmoid outputs, fp32; e 4 col-blocks + n 2
    {
        GSide s0 = {bufB, wh[3], wl[3], ball + 968, out_e, 224, 256, 256, 256, 1};
        GSide s1 = {bufB + 224, wh[7], wl[7], ball + 1224, out_v, 128, 128, 128, 128, 1};
        k_mgemm<<<GXM * 6, 256, 0, stream>>>(s0, s1, 4, 6, GXM, 352, dinv);
    }
}

// Round 11
// 465.072 us; speedup vs baseline: 1.0329x; 1.0329x over previous
//
#include <hip/hip_runtime.h>
#include <hip/hip_bf16.h>
#include <cstdint>
#include <cstddef>

typedef __hip_bfloat16 bf16;
typedef __attribute__((ext_vector_type(8))) short bf16x8;
typedef __attribute__((ext_vector_type(4))) float f32x4;

#define NN 50000
#define NE 400000

__device__ __forceinline__ float bf2f(unsigned short u) {
    return __uint_as_float(((unsigned)u) << 16);
}
__device__ __forceinline__ unsigned short f2bf(float f) {
    __hip_bfloat16 h = __float2bfloat16(f);
    return *reinterpret_cast<unsigned short*>(&h);
}
__device__ __forceinline__ float fin(float v) {
    return (v == v && v > -1e30f && v < 1e30f) ? v : 0.0f;
}
__device__ __forceinline__ float rd(const void* p, int i, int f) {
    return f ? ((const float*)p)[i] : bf2f(((const unsigned short*)p)[i]);
}

// async global -> LDS, 16B per lane, dest = wave-uniform base + lane*16
__device__ __forceinline__ void gl16(const void* g, void* l) {
    __builtin_amdgcn_global_load_lds(
        (const __attribute__((address_space(1))) unsigned int*)g,
        (__attribute__((address_space(3))) unsigned int*)l, 16, 0, 0);
}

// ---- inline dtype probe: 1 fp32 / 0 bf16. wave 0 computes, LDS-broadcast. ----
__device__ __forceinline__ int probe_flag(const unsigned* __restrict__ p, int words,
                                          int* sflag) {
    if (threadIdx.x < 64) {
        int lane = threadIdx.x;
        int zc = 0, bc = 0;
        #pragma unroll
        for (int c = 0; c < 4; ++c) {
            int idx = c * 64 + lane;
            int act = idx < words;
            unsigned w = act ? p[idx] : 0u;
            int isz = act && (w == 0u);
            int e = (w >> 7) & 0xFF;
            int isb = act && !isz && (e >= 100 && e <= 140);
            zc += __popcll(__ballot(isz));
            bc += __popcll(__ballot(isb));
        }
        int nz = words - zc;
        if (lane == 0) *sflag = (nz == 0 || 2 * bc >= nz) ? 0 : 1;
    }
    __syncthreads();
    return *sflag;
}

// ---- mega-prep: [wsplit segs 0..7 | bias 8 blocks | xin 3125 blocks] ----
struct Prep {
    const void* wsrc[8];
    unsigned short* pwh[8];
    unsigned short* pwl[8];
    int K[8], M[8], Kp[8];
    int b0[8];
    int biasStart, xinStart;
    const void* bsrc[8];
    int bM[8], bmp[8], bmo[8];
    float* ball;
    const void* x;
    const float* dinv;
    unsigned short* xs;
};

__global__ void k_prep(Prep P) {
    __shared__ int sflag;
    const int bid = blockIdx.x;

    if (bid >= P.xinStart) {
        // ---- xin: xs = bf16(x * dinv), stride 128 ----
        int f = probe_flag((const unsigned*)P.x, 256, &sflag);
        int t = (bid - P.xinStart) * 256 + threadIdx.x;
        if (t >= NN * 16) return;
        int i = t >> 4, c = (t & 15) * 8;
        float d = P.dinv[i];
        const float* xf = (const float*)P.x + (size_t)i * 128 + c;
        const unsigned short* xb = (const unsigned short*)P.x + (size_t)i * 128 + c;
        unsigned short o[8];
        #pragma unroll
        for (int j = 0; j < 8; ++j)
            o[j] = f2bf(fin(f ? xf[j] : bf2f(xb[j])) * d);
        *(uint4*)(P.xs + (size_t)i * 128 + c) = *(uint4*)o;
        return;
    }
    if (bid >= P.biasStart) {
        // ---- bias: zero-padded to bmp[l] ----
        int l = bid - P.biasStart;
        int words = P.bM[l] >> 1; if (words > 256) words = 256;
        int f = probe_flag((const unsigned*)P.bsrc[l], words, &sflag);
        int i = threadIdx.x;
        if (i < P.bmp[l])
            P.ball[P.bmo[l] + i] = (i < P.bM[l]) ? fin(rd(P.bsrc[l], i, f)) : 0.0f;
        return;
    }
    // ---- weight split: transposed bf16 hi/lo, [rows][Kp], zero-padded ----
    int seg = 0;
    #pragma unroll
    for (int t = 1; t < 8; ++t) if (bid >= P.b0[t]) seg = t;
    int words = (P.K[seg] * P.M[seg]) >> 1; if (words > 256) words = 256;
    int f = probe_flag((const unsigned*)P.wsrc[seg], words, &sflag);
    int n = bid - P.b0[seg];
    int k = threadIdx.x;
    int Kp = P.Kp[seg];
    if (k >= Kp) return;
    float v = 0.0f;
    if (k < P.K[seg] && n < P.M[seg])
        v = fin(rd(P.wsrc[seg], k * P.M[seg] + n, f));
    unsigned short hi = f2bf(v);
    unsigned short lo = f2bf(v - bf2f(hi));
    P.pwh[seg][(size_t)n * Kp + k] = hi;
    P.pwl[seg][(size_t)n * Kp + k] = lo;
}

// ---- repack edge list + degree count; ei int32/int64 flag computed inline ----
__global__ void k_repack(const int* __restrict__ ei,
                         int* __restrict__ src, int* __restrict__ dst,
                         int* __restrict__ deg) {
    __shared__ int sAny;
    if (threadIdx.x < 64) {
        int lane = threadIdx.x;
        int any = 0;
        #pragma unroll
        for (int c = 0; c < 32; ++c) {
            int idx = c * 64 + lane;
            int v = ei[2 * idx + 1];
            any |= (__ballot(v != 0) != 0ull) ? 1 : 0;
        }
        if (lane == 0) sAny = any;
    }
    __syncthreads();
    int f = sAny;
    int e = blockIdx.x * blockDim.x + threadIdx.x;
    if (e >= NE) return;
    int s, d;
    if (f) { s = ei[e]; d = ei[NE + e]; }
    else   { s = ei[2 * e]; d = ei[2 * (NE + e)]; }
    s = min(max(s, 0), NN - 1);
    d = min(max(d, 0), NN - 1);
    src[e] = s;
    dst[e] = d;
    atomicAdd(&deg[d], 1);
}

__global__ void k_scan1(const int* __restrict__ deg, int* __restrict__ rowp,
                        int* __restrict__ part) {
    __shared__ int s[512];
    int tid = threadIdx.x, i = blockIdx.x * 512 + tid;
    int v = (i < NN) ? deg[i] : 0;
    s[tid] = v;
    __syncthreads();
    for (int off = 1; off < 512; off <<= 1) {
        int t = (tid >= off) ? s[tid - off] : 0;
        __syncthreads();
        s[tid] += t;
        __syncthreads();
    }
    if (i < NN) rowp[i] = s[tid] - v;
    if (tid == 511) part[blockIdx.x] = s[511];
}

// ---- scan finalize: per-block partial reduce, dinv, cursor=0 ----
__global__ void k_scan3b(int* __restrict__ rowp, const int* __restrict__ part,
                         const int* __restrict__ deg, float* __restrict__ dinv,
                         int* __restrict__ cursor) {
    __shared__ int sS;
    const int b = blockIdx.x;
    const int g = b >> 1;
    if (threadIdx.x < 64) {
        int lane = threadIdx.x;
        int v = 0;
        if (lane < g) v += part[lane];
        if (64 + lane < g) v += part[64 + lane];
        #pragma unroll
        for (int o = 1; o < 64; o <<= 1) v += __shfl_xor(v, o);
        if (lane == 0) sS = v;
    }
    __syncthreads();
    int S = sS;
    int i = b * 256 + threadIdx.x;
    if (i < NN) {
        rowp[i] += S;
        dinv[i] = rsqrtf((float)deg[i] + 1.0f);
        cursor[i] = 0;
    }
    if (i == 0) rowp[NN] = NE;
}

__global__ void k_fill(const int* __restrict__ src, const int* __restrict__ dst,
                       const int* __restrict__ rowp, int* __restrict__ cursor,
                       int* __restrict__ colv) {
    int e = blockIdx.x * blockDim.x + threadIdx.x;
    if (e >= NE) return;
    int d = dst[e];
    int p = atomicAdd(&cursor[d], 1);
    colv[rowp[d] + p] = src[e];
}

// ---- CSR gather: out[i]=dinv[i]*(in[i]+sum in[colv[j]]) ----
__launch_bounds__(256)
__global__ void k_gather(const unsigned short* __restrict__ in, int istride,
                         unsigned short* __restrict__ out, int ostride, int lanes,
                         const int* __restrict__ rowp, const int* __restrict__ colv,
                         const float* __restrict__ dinv) {
    const int node = blockIdx.x * 4 + (threadIdx.x >> 6);
    if (node >= NN) return;
    const int lane = threadIdx.x & 63;
    const int beg = rowp[node], end = rowp[node + 1];
    float a[8] = {0.f, 0.f, 0.f, 0.f, 0.f, 0.f, 0.f, 0.f};
    auto accq = [&](uint4 q) {
        unsigned v[4] = {q.x, q.y, q.z, q.w};
        #pragma unroll
        for (int t = 0; t < 4; ++t) {
            a[2 * t] += bf2f(v[t] & 0xFFFF); a[2 * t + 1] += bf2f(v[t] >> 16);
        }
    };
    if (lanes <= 16) {
        const int slot = lane >> 4;
        const int l8 = lane & 15;
        const bool on = l8 < lanes;
        const size_t off = (size_t)l8 * 8;
        if (slot == 0 && on)
            accq(*(const uint4*)(in + (size_t)node * istride + off));
        for (int j = beg + slot; j < end; j += 4) {
            const int s = colv[j];
            if (on) accq(*(const uint4*)(in + (size_t)s * istride + off));
        }
        #pragma unroll
        for (int t = 0; t < 8; ++t) {
            a[t] += __shfl_xor(a[t], 16);
            a[t] += __shfl_xor(a[t], 32);
        }
        if (lane < lanes) {
            float d = dinv[node];
            unsigned short o[8];
            #pragma unroll
            for (int t = 0; t < 8; ++t) o[t] = f2bf(a[t] * d);
            *(uint4*)(out + (size_t)node * ostride + (size_t)lane * 8) = *(uint4*)o;
        }
    } else {
        const bool on = lane < lanes;
        const size_t off = (size_t)lane * 8;
        if (on) accq(*(const uint4*)(in + (size_t)node * istride + off));
        int j = beg;
        for (; j + 1 < end; j += 2) {
            int s0 = colv[j], s1 = colv[j + 1];
            if (on) {
                uint4 q0 = *(const uint4*)(in + (size_t)s0 * istride + off);
                uint4 q1 = *(const uint4*)(in + (size_t)s1 * istride + off);
                accq(q0); accq(q1);
            }
        }
        if (j < end) {
            int s0 = colv[j];
            if (on) accq(*(const uint4*)(in + (size_t)s0 * istride + off));
        }
        if (on) {
            float d = dinv[node];
            unsigned short o[8];
            #pragma unroll
            for (int t = 0; t < 8; ++t) o[t] = f2bf(a[t] * d);
            *(uint4*)(out + (size_t)node * ostride + off) = *(uint4*)o;
        }
    }
}

// ---- merged GEMM side params ----
struct GSide {
    const unsigned short* A;
    const unsigned short* Wh;
    const unsigned short* Wl;
    const float* bias;
    void* out;
    int Kp, ostride, M, OutW, act;
};

// ---- MFMA GEMM: 128x64 tile (wave = 32 rows x 64 cols), 32KB LDS -> 4-5
//      blocks/CU for latency hiding. r5-proven pipeline: gl16 staging,
//      XOR-swizzled LDS, 2-ahead counted-vmcnt (steady vmcnt(4), never drain
//      in-loop), dual-side 1-D grid with XCD group swizzle, LDS epilogue. ----
__launch_bounds__(256, 4)
__global__ void k_mgemm(GSide s0, GSide s1, int ySplit, int NY, int NB, int astride,
                        const float* __restrict__ dinv) {
    __shared__ __align__(16) unsigned char ldsraw[32768];
    auto sA  = reinterpret_cast<unsigned short (*)[128][32]>(ldsraw);          // 16K
    auto sBh = reinterpret_cast<unsigned short (*)[64][32]>(ldsraw + 16384);   // 8K
    auto sBl = reinterpret_cast<unsigned short (*)[64][32]>(ldsraw + 24576);   // 8K

    const int tid = threadIdx.x;
    const int wave = tid >> 6, lane = tid & 63;
    const int quad = lane >> 4, m16 = lane & 15;

    // XCD grouping: the NY col-blocks of one x-tile land on the same XCD
    const int NBa = NB & ~7;
    const int swcut = NBa * NY;
    int b = blockIdx.x, x, yv;
    if (b < swcut) {
        x = (b / (8 * NY)) * 8 + (b & 7);
        yv = (b >> 3) % NY;
    } else {
        int r = b - swcut, rem = NB - NBa;
        x = rem ? (NBa + r % rem) : 0;
        yv = rem ? (r / rem) : 0;
    }

    GSide S; int ycol;
    if (yv < ySplit) { S = s0; ycol = yv; }
    else             { S = s1; ycol = yv - ySplit; }
    const int row0 = x * 128, col0 = ycol * 64;
    const int Kp = S.Kp;

    // staging: lane -> (row, 16B unit); A: wave stages rows [wave*32, +32)
    //          B: wave stages rows [wave*16, +16) of the 64-row col panel
    const int lr = lane >> 2;
    const int swz = ((lane >> 2) ^ (lane >> 4)) & 3;
    const int su = ((lane & 3) ^ swz) * 8;

    int ar1 = row0 + wave * 32 + lr;      if (ar1 >= NN) ar1 = NN - 1;
    int ar2 = row0 + wave * 32 + 16 + lr; if (ar2 >= NN) ar2 = NN - 1;
    const unsigned short* gA1 = S.A + (size_t)ar1 * astride + su;
    const unsigned short* gA2 = S.A + (size_t)ar2 * astride + su;
    const int br = col0 + wave * 16 + lr;
    const unsigned short* gBh1 = S.Wh + (size_t)br * Kp + su;
    const unsigned short* gBl1 = S.Wl + (size_t)br * Kp + su;

    f32x4 zz = {0.f, 0.f, 0.f, 0.f};
    f32x4 acc[2][4];
    #pragma unroll
    for (int i = 0; i < 2; ++i)
        #pragma unroll
        for (int j = 0; j < 4; ++j) acc[i][j] = zz;

    const int rs = (quad ^ ((m16 & 3) ^ ((m16 >> 2) & 3))) * 8;
    const int nk = Kp >> 5;

    auto stage = [&](int bb, int k0) {           // 4 vmem ops per wave
        gl16(gA1 + k0,  &sA[bb][wave * 32][0]);
        gl16(gA2 + k0,  &sA[bb][wave * 32 + 16][0]);
        gl16(gBh1 + k0, &sBh[bb][wave * 16][0]);
        gl16(gBl1 + k0, &sBl[bb][wave * 16][0]);
    };

    // 2-ahead prologue: stages 0 and 1 in flight (4 vmem ops each)
    stage(0, 0);
    if (nk > 1) stage(1, 32);

    for (int ks = 0; ks < nk; ++ks) {
        const int cur = ks & 1;
        // wait only MY stage-ks loads (4 newer from stage ks+1 stay in flight)
        if (ks + 1 < nk) asm volatile("s_waitcnt vmcnt(4)" ::: "memory");
        else             asm volatile("s_waitcnt vmcnt(0)" ::: "memory");
        __builtin_amdgcn_s_barrier();        // all waves' stage-ks landed
        bf16x8 fa[2], fh[4], fl[4];
        #pragma unroll
        for (int i = 0; i < 2; ++i)
            fa[i] = *(const bf16x8*)&sA[cur][wave * 32 + i * 16 + m16][rs];
        #pragma unroll
        for (int j = 0; j < 4; ++j) {
            fh[j] = *(const bf16x8*)&sBh[cur][j * 16 + m16][rs];
            fl[j] = *(const bf16x8*)&sBl[cur][j * 16 + m16][rs];
        }
        asm volatile("s_waitcnt lgkmcnt(0)" ::: "memory");
        __builtin_amdgcn_sched_barrier(0);
        __builtin_amdgcn_s_barrier();        // buf cur consumed -> free to overwrite
        if (ks + 2 < nk) stage(cur, (ks + 2) * 32);   // refill freed buffer
        #pragma unroll
        for (int i = 0; i < 2; ++i)
            #pragma unroll
            for (int j = 0; j < 4; ++j) {
                acc[i][j] = __builtin_amdgcn_mfma_f32_16x16x32_bf16(fa[i], fh[j], acc[i][j], 0, 0, 0);
                acc[i][j] = __builtin_amdgcn_mfma_f32_16x16x32_bf16(fa[i], fl[j], acc[i][j], 0, 0, 0);
            }
    }

    // ---- epilogue: stage per-wave 16x64 f32 tile in LDS, store coalesced ----
    float* eps = (float*)(ldsraw + (size_t)wave * 4352);
    #pragma unroll
    for (int i = 0; i < 2; ++i) {
        #pragma unroll
        for (int j = 0; j < 4; ++j) {
            int col = col0 + j * 16 + m16;
            float bcol = (col < S.M) ? S.bias[col] : 0.0f;
            #pragma unroll
            for (int r = 0; r < 4; ++r) {
                float v = acc[i][j][r] + bcol;
                if (S.act) v = (col < S.M) ? 1.0f / (1.0f + __expf(-v)) : 0.0f;
                else       v = (col < S.M) ? fmaxf(v, 0.0f) : 0.0f;
                eps[(quad * 4 + r) * 68 + j * 16 + m16] = v;
            }
        }
        asm volatile("s_waitcnt lgkmcnt(0)" ::: "memory");
        __builtin_amdgcn_sched_barrier(0);
        #pragma unroll
        for (int it = 0; it < 4; ++it) {
            int lr2 = it * 4 + (lane >> 4);
            int c4 = (lane & 15) * 4;
            float4 w = *(float4*)&eps[lr2 * 68 + c4];
            int grow = row0 + wave * 32 + i * 16 + lr2;
            int gcol = col0 + c4;
            if (grow < NN && gcol < S.OutW) {
                if (S.act) {
                    // final outputs: never re-read -> nontemporal, keep L2 for A
                    float* dp = (float*)S.out + (size_t)grow * S.ostride + gcol;
                    __builtin_nontemporal_store(w.x, dp);
                    __builtin_nontemporal_store(w.y, dp + 1);
                    __builtin_nontemporal_store(w.z, dp + 2);
                    __builtin_nontemporal_store(w.w, dp + 3);
                } else {
                    float d = dinv[grow];
                    unsigned o0 = f2bf(w.x * d) | ((unsigned)f2bf(w.y * d) << 16);
                    unsigned o1 = f2bf(w.z * d) | ((unsigned)f2bf(w.w * d) << 16);
                    uint2 u; u.x = o0; u.y = o1;
                    *(uint2*)((unsigned short*)S.out + (size_t)grow * S.ostride + gcol) = u;
                }
            }
        }
        asm volatile("s_waitcnt lgkmcnt(0)" ::: "memory");
        __builtin_amdgcn_sched_barrier(0);
    }
}

__global__ void k_sentinel(float* __restrict__ out, int n) {
    int i = blockIdx.x * blockDim.x + threadIdx.x;
    if (i < n) out[i] = 4.0f;
}

extern "C" void kernel_launch(void* const* d_in, const int* in_sizes, int n_in,
                              void* d_out, int out_size, void* d_ws, size_t ws_size,
                              hipStream_t stream) {
    const int* ei = (const int*)d_in[1];
    float* out_e = (float*)d_out;
    float* out_v = out_e + (size_t)NN * 256;

    // weight storage: l=0 merged [W1e pad168 | W1n pad->384] x128; l=4 unused
    const int KpW[8] = {128, 192, 192, 224, 0, 128, 128, 128};
    const int MpW[8] = {384, 256, 256, 256, 0, 128, 128, 128};

    char* wsb = (char*)d_ws;
    size_t o = 0;
    auto align = [](size_t v) { return (v + 255) & ~(size_t)255; };
    int*   colv   = (int*)(wsb + o);  o = align(o + (size_t)NE * 4);
    int*   deg    = (int*)(wsb + o);  o = align(o + (size_t)NN * 4);
    int*   cursor = (int*)(wsb + o);  o = align(o + (size_t)NN * 4);
    int*   rowp   = (int*)(wsb + o);  o = align(o + (size_t)(NN + 1) * 4);
    int*   part   = (int*)(wsb + o);  o = align(o + 512);
    float* dinv   = (float*)(wsb + o); o = align(o + (size_t)NN * 4);
    unsigned short* wh[8]; unsigned short* wl[8];
    for (int l = 0; l < 8; ++l) {
        size_t wel = (size_t)MpW[l] * KpW[l];
        wh[l] = (unsigned short*)(wsb + o); o = align(o + wel * 2);
        wl[l] = (unsigned short*)(wsb + o); o = align(o + wel * 2);
    }
    float* ball = (float*)(wsb + o); o = align(o + 1376 * 4);
    unsigned short* bufA = (unsigned short*)(wsb + o); o = align(o + (size_t)NN * 352 * 2);
    unsigned short* bufB = (unsigned short*)(wsb + o); o = align(o + (size_t)NN * 352 * 2);
    int* src32 = (int*)bufB;
    int* dst32 = src32 + NE;
    if (o > ws_size) {
        k_sentinel<<<(out_size + 255) / 256, 256, 0, stream>>>(out_e, out_size);
        return;
    }

    // bias layout: [b1e 168 | b1n 128 | b2e 192 | b2n 128 | b3e 224 | b3n 128 | b4e 256 | b4n 128]
    const int moff[8] = {0, 296, 616, 968, 168, 488, 840, 1224};
    const int mpad[8] = {168, 192, 224, 256, 128, 128, 128, 128};

    const int EB = (NE + 255) / 256;
    const int NB512 = (NN + 511) / 512;
    const int GX = (NN + 127) / 128;          // 391
    const int GN = (NN + 3) / 4;

    // ---- CSR build ----
    hipMemsetAsync(deg, 0, (size_t)NN * 4, stream);
    k_repack<<<EB, 256, 0, stream>>>(ei, src32, dst32, deg);
    k_scan1<<<NB512, 512, 0, stream>>>(deg, rowp, part);
    k_scan3b<<<(NN + 255) / 256, 256, 0, stream>>>(rowp, part, deg, dinv, cursor);
    k_fill<<<EB, 256, 0, stream>>>(src32, dst32, rowp, cursor, colv);

    // ---- mega-prep: weight split (hi/lo) + biases + xin, one launch ----
    {
        Prep P;
        const void* srcs[8] = {d_in[2], d_in[10], d_in[4], d_in[12],
                               d_in[6], d_in[14], d_in[8], d_in[16]};
        unsigned short* whp[8] = {wh[0], wh[0] + 168 * 128, wh[1], wh[5],
                                  wh[2], wh[6], wh[3], wh[7]};
        unsigned short* wlp[8] = {wl[0], wl[0] + 168 * 128, wl[1], wl[5],
                                  wl[2], wl[6], wl[3], wl[7]};
        const int Ks[8]   = {128, 128, 166, 128, 192, 128, 218, 128};
        const int Ms[8]   = {166, 128, 192, 128, 218, 128, 256, 128};
        const int Kps[8]  = {128, 128, 192, 128, 192, 128, 224, 128};
        const int rows[8] = {168, 216, 256, 128, 256, 128, 256, 128};
        int acc = 0;
        for (int s = 0; s < 8; ++s) {
            P.wsrc[s] = srcs[s]; P.pwh[s] = whp[s]; P.pwl[s] = wlp[s];
            P.K[s] = Ks[s]; P.M[s] = Ms[s]; P.Kp[s] = Kps[s];
            P.b0[s] = acc; acc += rows[s];
        }
        P.biasStart = acc;            // 1536
        P.xinStart = acc + 8;         // 1544
        const int bMv[8] = {166, 192, 218, 256, 128, 128, 128, 128};
        for (int l = 0; l < 8; ++l) {
            P.bsrc[l] = d_in[3 + 2 * l];
            P.bM[l] = bMv[l]; P.bmp[l] = mpad[l]; P.bmo[l] = moff[l];
        }
        P.ball = ball;
        P.x = d_in[0];
        P.dinv = dinv;
        P.xs = bufA;
        const int xinBlocks = (NN * 16 + 255) / 256;   // 3125
        k_prep<<<P.xinStart + xinBlocks, 256, 0, stream>>>(P);
    }

    // gather0: bufA(128) -> bufB (stride 128)
    k_gather<<<GN, 256, 0, stream>>>(bufA, 128, bufB, 128, 16, rowp, colv, dinv);

    // L1 merged (e+n): bufB(128) -> bufA (stride 296 = [e168 | n128]), 5 col-blocks
    {
        GSide s0 = {bufB, wh[0], wl[0], ball, bufA, 128, 296, 296, 296, 0};
        k_mgemm<<<GX * 5, 256, 0, stream>>>(s0, s0, 5, 5, GX, 128, dinv);
    }
    k_gather<<<GN, 256, 0, stream>>>(bufA, 296, bufB, 296, 37, rowp, colv, dinv);

    // L2: e (K=192, 3 col-blocks) + n (K=128, 2 col-blocks), out stride 320
    {
        GSide s0 = {bufB, wh[1], wl[1], ball + 296, bufA, 192, 320, 192, 192, 0};
        GSide s1 = {bufB + 168, wh[5], wl[5], ball + 488, bufA + 192, 128, 320, 128, 128, 0};
        k_mgemm<<<GX * 5, 256, 0, stream>>>(s0, s1, 3, 5, GX, 296, dinv);
    }
    k_gather<<<GN, 256, 0, stream>>>(bufA, 320, bufB, 320, 40, rowp, colv, dinv);

    // L3: e (K=192, 4 col-blocks -> 224 wide) + n (2), out stride 352
    {
        GSide s0 = {bufB, wh[2], wl[2], ball + 616, bufA, 192, 352, 218, 224, 0};
        GSide s1 = {bufB + 192, wh[6], wl[6], ball + 840, bufA + 224, 128, 352, 128, 128, 0};
        k_mgemm<<<GX * 6, 256, 0, stream>>>(s0, s1, 4, 6, GX, 320, dinv);
    }
    k_gather<<<GN, 256, 0, stream>>>(bufA, 352, bufB, 352, 44, rowp, colv, dinv);

    // L4: sigmoid outputs, fp32; e 4 col-blocks + n 2
    {
        GSide s0 = {bufB, wh[3], wl[3], ball + 968, out_e, 224, 256, 256, 256, 1};
        GSide s1 = {bufB + 224, wh[7], wl[7], ball + 1224, out_v, 128, 128, 128, 128, 1};
        k_mgemm<<<GX * 6, 256, 0, stream>>>(s0, s1, 4, 6, GX, 352, dinv);
    }
}